// Round 16
// baseline (93.528 us; speedup 1.0000x reference)
//
#include <hip/hip_runtime.h>

#define HH 8
#define LL 4
#define PP 2
#define DD 32
#define CC 256
#define NVV 21760
#define NQQ 1000
#define BB 4
#define NQT (BB * NQQ)   // 4000 total queries

typedef __attribute__((ext_vector_type(8))) short short8;
typedef __attribute__((ext_vector_type(4))) short shortv4;
typedef __attribute__((ext_vector_type(4))) float f32x4;

__device__ __forceinline__ unsigned short f2bf(float f) {
    unsigned u = __float_as_uint(f);
    u += 0x7FFF + ((u >> 16) & 1);  // round-to-nearest-even
    return (unsigned short)(u >> 16);
}
__device__ __forceinline__ float bf2f(unsigned short h) {
    return __uint_as_float(((unsigned)h) << 16);
}
__device__ __forceinline__ unsigned cvtpk(float lo, float hi) {
    unsigned r;
    asm volatile("v_cvt_pk_bf16_f32 %0, %1, %2" : "=v"(r) : "v"(lo), "v"(hi));
    return r;
}

// ---------------------------------------------------------------------------
// Kernel 0: weight prep. Block c (=k row, 0..255), thread n. Coalesced reads.
//  WTf: FRAGMENT-EXACT layout for the wave-autonomous GEMM:
//       WTf[w][cf][s][lane][j] (w=n>>6, cf=(n>>4)&3, lane=q*16+(n&15),
//       s=c>>5, q=(c>>3)&3, j=c&7) -> each wave's B-frag load is one fully
//       contiguous 1KB dwordx4 per (cf,s).
//  W1T[n][c] = bf16([W_off|W_attn][c][n]),  WoT[n][c] = bf16(W_out[c][n])
// ---------------------------------------------------------------------------
__global__ __launch_bounds__(256) void prep_kernel(
    const float* __restrict__ Wv, const float* __restrict__ Woff,
    const float* __restrict__ Wattn, const float* __restrict__ Wout,
    unsigned short* __restrict__ WTf, unsigned short* __restrict__ W1T,
    unsigned short* __restrict__ WoT)
{
    const int c = blockIdx.x;   // k index 0..255
    const int n = threadIdx.x;  // output col 0..255
    {
        int w = n >> 6, cf = (n >> 4) & 3, lrr = n & 15;
        int s = c >> 5, qq = (c >> 3) & 3, j = c & 7;
        size_t idx =
            ((((size_t)(w * 4 + cf) * 8 + s) * 64) + qq * 16 + lrr) * 8 + j;
        WTf[idx] = f2bf(Wv[c * CC + n]);
    }
    if (n < 192) {
        float x = (n < 128) ? Woff[c * 128 + n] : Wattn[c * 64 + (n - 128)];
        W1T[n * CC + c] = f2bf(x);
    }
    WoT[n * CC + c] = f2bf(Wout[c * CC + n]);
}

// ---------------------------------------------------------------------------
// Kernel 1: v[b*NVV+n][256] (bf16, row-major) = value @ W_val + b_val.
// WAVE-AUTONOMOUS: zero LDS, ZERO BARRIERS. Every prior variant (R4-R14)
// coupled 4-8 waves with block barriers around LDS staging -> the block
// advanced at the slowest DMA and <=2 blocks/CU left no TLP; all plateaued
// at 45-57us. Here each wave runs free; a stalled wave blocks only itself
// and 12 waves/CU interleave (VGPR-only occupancy, launch_bounds(256,3)).
//   - block = 32 rows (A L1-shared across the 4 waves), wave = 64 cols.
//   - A: direct global->VGPR float4 pairs, reg-dbuf depth 2.
//   - B: 1KB contiguous frag loads from WTf (fragment-exact layout),
//     reg-dbuf depth 2; 32KB/wave from L2.
//   - 8 k-steps x {2 cvt_pk-packs + 8 MFMA}; direct-store epilogue.
// ---------------------------------------------------------------------------
__global__ __launch_bounds__(256, 3) void valproj_mfma(
    const float* __restrict__ value, const unsigned short* __restrict__ WTf,
    const float* __restrict__ bv, unsigned short* __restrict__ v_out)
{
    const int tid = threadIdx.x;
    const int lane = tid & 63;
    const int w = tid >> 6;        // wave 0..3 -> 64-col strip
    const int lr = lane & 15;
    const int q = lane >> 4;       // k-chunk / row-quad
    const int r0 = blockIdx.x * 32;   // 2720 blocks; 87040/32

    const float* arow0 = value + (size_t)(r0 + lr) * CC + q * 8;
    const float* arow1 = value + (size_t)(r0 + 16 + lr) * CC + q * 8;
    const unsigned short* bbase = WTf + (size_t)w * 16384 + (size_t)lane * 8;

    f32x4 acc[2][4] = {};
    float4 a[2][2][2];   // [pipe][rf][half]
    short8 bp[2][4];     // [pipe][cf]

#define LA(s, p)                                                            \
    {                                                                       \
        a[p][0][0] = *(const float4*)(arow0 + (s) * 32);                    \
        a[p][0][1] = *(const float4*)(arow0 + (s) * 32 + 4);                \
        a[p][1][0] = *(const float4*)(arow1 + (s) * 32);                    \
        a[p][1][1] = *(const float4*)(arow1 + (s) * 32 + 4);                \
    }
#define LB(s, p)                                                            \
    {                                                                       \
        _Pragma("unroll") for (int cf = 0; cf < 4; ++cf)                    \
            bp[p][cf] =                                                     \
                *(const short8*)(bbase + (size_t)(cf * 8 + (s)) * 512);     \
    }

    LA(0, 0); LB(0, 0);
    LA(1, 1); LB(1, 1);

#pragma unroll
    for (int s = 0; s < 8; ++s) {
        const int cur = s & 1;
        short8 af[2];
#pragma unroll
        for (int rf = 0; rf < 2; ++rf) {
            float4 f0 = a[cur][rf][0], f1 = a[cur][rf][1];
            uint4 uv = {cvtpk(f0.x, f0.y), cvtpk(f0.z, f0.w),
                        cvtpk(f1.x, f1.y), cvtpk(f1.z, f1.w)};
            af[rf] = __builtin_bit_cast(short8, uv);
        }
        short8 bf[4];
#pragma unroll
        for (int cf = 0; cf < 4; ++cf) bf[cf] = bp[cur][cf];
        if (s < 6) { LA(s + 2, cur); LB(s + 2, cur); }
#pragma unroll
        for (int rf = 0; rf < 2; ++rf)
#pragma unroll
            for (int cf = 0; cf < 4; ++cf)
                acc[rf][cf] = __builtin_amdgcn_mfma_f32_16x16x32_bf16(
                    af[rf], bf[cf], acc[rf][cf], 0, 0, 0);
    }
#undef LA
#undef LB

    // epilogue: direct stores, v row-major [row][256] (R13-verified mapping)
#pragma unroll
    for (int rf = 0; rf < 2; ++rf)
#pragma unroll
        for (int r = 0; r < 4; ++r) {
            size_t rbase = (size_t)(r0 + rf * 16 + q * 4 + r) * 256;
#pragma unroll
            for (int cf = 0; cf < 4; ++cf) {
                int col = w * 64 + cf * 16 + lr;
                v_out[rbase + col] = f2bf(acc[rf][cf][r] + bv[col]);
            }
        }
}

// ---------------------------------------------------------------------------
// Kernel 2: logits[4000,192] = query @ [W_off|W_attn] + bias.
// BM=32, BK=64 (4 iters), 4 waves x 48 cols. Padded LDS rows (72).
// ---------------------------------------------------------------------------
__global__ __launch_bounds__(256) void logits_mfma(
    const float* __restrict__ query, const unsigned short* __restrict__ W1T,
    const float* __restrict__ b_off, const float* __restrict__ b_attn,
    float* __restrict__ logits)
{
    __shared__ unsigned short As[32][72];
    __shared__ unsigned short Bsl[192][72];
    const int tid = threadIdx.x;
    const int lane = tid & 63;
    const int wave = tid >> 6;
    const int bm = blockIdx.x * 32;  // 125 blocks * 32 = 4000
    const int lr = lane & 15;
    const int q = lane >> 4;
    f32x4 acc[2][3] = {};

    for (int k0 = 0; k0 < CC; k0 += 64) {
        float4 a[2];
        short8 wv[6];
#pragma unroll
        for (int i = 0; i < 2; ++i) {
            int u = tid + 256 * i;  // 512 float4 units: row=u>>4, col4=(u&15)*4
            a[i] = *(const float4*)&query[(size_t)(bm + (u >> 4)) * CC + k0 +
                                          (u & 15) * 4];
        }
#pragma unroll
        for (int i = 0; i < 6; ++i) {
            int u = tid + 256 * i;  // 1536 16B units: n=u>>3, j=u&7
            wv[i] = *(const short8*)&W1T[(size_t)(u >> 3) * CC + k0 + (u & 7) * 8];
        }
        __syncthreads();
#pragma unroll
        for (int i = 0; i < 2; ++i) {
            int u = tid + 256 * i;
            shortv4 p;
            p[0] = (short)f2bf(a[i].x); p[1] = (short)f2bf(a[i].y);
            p[2] = (short)f2bf(a[i].z); p[3] = (short)f2bf(a[i].w);
            *(shortv4*)&As[u >> 4][(u & 15) * 4] = p;
        }
#pragma unroll
        for (int i = 0; i < 6; ++i) {
            int u = tid + 256 * i;
            *(short8*)&Bsl[u >> 3][(u & 7) * 8] = wv[i];
        }
        __syncthreads();

#pragma unroll
        for (int kk = 0; kk < 2; ++kk) {
            short8 afr[2], bfr[3];
#pragma unroll
            for (int mf = 0; mf < 2; ++mf)
                afr[mf] = *(const short8*)&As[mf * 16 + lr][kk * 32 + q * 8];
#pragma unroll
            for (int nf = 0; nf < 3; ++nf)
                bfr[nf] =
                    *(const short8*)&Bsl[wave * 48 + nf * 16 + lr][kk * 32 + q * 8];
#pragma unroll
            for (int mf = 0; mf < 2; ++mf)
#pragma unroll
                for (int nf = 0; nf < 3; ++nf)
                    acc[mf][nf] = __builtin_amdgcn_mfma_f32_16x16x32_bf16(
                        afr[mf], bfr[nf], acc[mf][nf], 0, 0, 0);
        }
        __syncthreads();
    }

#pragma unroll
    for (int nf = 0; nf < 3; ++nf) {
        int col = wave * 48 + nf * 16 + lr;
        float bias = (col < 128) ? b_off[col] : b_attn[col - 128];
#pragma unroll
        for (int mf = 0; mf < 2; ++mf)
#pragma unroll
            for (int r = 0; r < 4; ++r) {
                int m = bm + mf * 16 + q * 4 + r;
                logits[(size_t)m * 192 + col] = acc[mf][nf][r] + bias;
            }
    }
}

// ---------------------------------------------------------------------------
// Kernel 3: sampling. One block per query (4000 blocks). Fuses softmax.
// v is ROW-MAJOR [b*NVV+n][256]; thread (h,d) gathers 8 samples x 4 corners.
// ---------------------------------------------------------------------------
__global__ __launch_bounds__(256) void sample_kernel(
    const float* __restrict__ logits,  // [4000][192]
    const float* __restrict__ refp,    // [B,NQ,L,2]
    const unsigned short* __restrict__ v,  // [B*NV][256] bf16
    unsigned short* __restrict__ mid)      // [4000][256] bf16
{
    __shared__ float offl[128];
    __shared__ float attnl[64];
    __shared__ float refl[8];

    const int qy = blockIdx.x;  // b*NQQ + nq
    const int b = qy / NQQ;
    const int tid = threadIdx.x;

    if (tid < 192) {
        float t = logits[(size_t)qy * 192 + tid];
        if (tid < 128) offl[tid] = t;
        else attnl[tid - 128] = t;
    } else if (tid < 200) {
        refl[tid - 192] = refp[(size_t)qy * 8 + (tid - 192)];
    }
    __syncthreads();

    if (tid < 8) {
        float m = -1e30f;
#pragma unroll
        for (int j = 0; j < 8; ++j) m = fmaxf(m, attnl[tid * 8 + j]);
        float s = 0.f, e[8];
#pragma unroll
        for (int j = 0; j < 8; ++j) {
            e[j] = __expf(attnl[tid * 8 + j] - m);
            s += e[j];
        }
        float inv = 1.f / s;
#pragma unroll
        for (int j = 0; j < 8; ++j) attnl[tid * 8 + j] = e[j] * inv;
    }
    __syncthreads();

    const int h = tid >> 5, d = tid & 31;
    const int starts[4] = {0, 16384, 20480, 21504};
    const float szs[4] = {128.f, 64.f, 32.f, 16.f};

    float acc = 0.f;
#pragma unroll
    for (int l = 0; l < LL; ++l) {
        const float S = szs[l];
        const int Wl = (int)S;
        const float refx = refl[l * 2 + 0];
        const float refy = refl[l * 2 + 1];
        const unsigned short* vl =
            v + (size_t)(b * NVV + starts[l]) * 256 + h * 32 + d;
#pragma unroll
        for (int p = 0; p < PP; ++p) {
            const int oi = h * 16 + l * 4 + p * 2;
            float lx = refx + offl[oi + 0] / S;
            float ly = refy + offl[oi + 1] / S;
            float x = lx * S - 0.5f;
            float y = ly * S - 0.5f;
            float x0f = floorf(x), y0f = floorf(y);
            float fx = x - x0f, fy = y - y0f;
            int x0 = (int)x0f, y0 = (int)y0f;
            float a = attnl[h * 8 + l * 2 + p];
            float sacc = 0.f;
#pragma unroll
            for (int dy = 0; dy < 2; ++dy) {
#pragma unroll
                for (int dx = 0; dx < 2; ++dx) {
                    int xi = x0 + dx, yi = y0 + dy;
                    float wgt = (dx ? fx : 1.f - fx) * (dy ? fy : 1.f - fy);
                    bool valid = (xi >= 0) && (xi < Wl) && (yi >= 0) && (yi < Wl);
                    int xc = min(max(xi, 0), Wl - 1);
                    int yc = min(max(yi, 0), Wl - 1);
                    float g = bf2f(vl[(size_t)(yc * Wl + xc) * 256]);
                    sacc += g * (valid ? wgt : 0.f);
                }
            }
            acc += a * sacc;
        }
    }
    mid[(size_t)qy * CC + h * 32 + d] = f2bf(acc);
}

// ---------------------------------------------------------------------------
// Kernel 4: out[4000,256] = mid_bf16 @ W_out_bf16 + b_out.
// BM=32, BK=64 (4 iters), 4 waves x 64 cols. Padded LDS rows (72).
// ---------------------------------------------------------------------------
__global__ __launch_bounds__(256) void out_mfma(
    const unsigned short* __restrict__ mid,
    const unsigned short* __restrict__ WoT, const float* __restrict__ b_out,
    float* __restrict__ out)
{
    __shared__ unsigned short As[32][72];
    __shared__ unsigned short Bso[256][72];
    const int tid = threadIdx.x;
    const int lane = tid & 63;
    const int wave = tid >> 6;
    const int bm = blockIdx.x * 32;
    const int lr = lane & 15;
    const int q = lane >> 4;
    f32x4 acc[2][4] = {};

    for (int k0 = 0; k0 < CC; k0 += 64) {
        short8 a0 = *(const short8*)&mid[(size_t)(bm + (tid >> 3)) * CC + k0 +
                                         (tid & 7) * 8];
        short8 wv[8];
#pragma unroll
        for (int i = 0; i < 8; ++i) {
            int u = tid + 256 * i;  // 2048 16B units: n=u>>3, j=u&7
            wv[i] = *(const short8*)&WoT[(size_t)(u >> 3) * CC + k0 + (u & 7) * 8];
        }
        __syncthreads();
        *(short8*)&As[tid >> 3][(tid & 7) * 8] = a0;
#pragma unroll
        for (int i = 0; i < 8; ++i) {
            int u = tid + 256 * i;
            *(short8*)&Bso[u >> 3][(u & 7) * 8] = wv[i];
        }
        __syncthreads();

#pragma unroll
        for (int kk = 0; kk < 2; ++kk) {
            short8 afr[2], bfr[4];
#pragma unroll
            for (int mf = 0; mf < 2; ++mf)
                afr[mf] = *(const short8*)&As[mf * 16 + lr][kk * 32 + q * 8];
#pragma unroll
            for (int nf = 0; nf < 4; ++nf)
                bfr[nf] =
                    *(const short8*)&Bso[wave * 64 + nf * 16 + lr][kk * 32 + q * 8];
#pragma unroll
            for (int mf = 0; mf < 2; ++mf)
#pragma unroll
                for (int nf = 0; nf < 4; ++nf)
                    acc[mf][nf] = __builtin_amdgcn_mfma_f32_16x16x32_bf16(
                        afr[mf], bfr[nf], acc[mf][nf], 0, 0, 0);
        }
        __syncthreads();
    }

#pragma unroll
    for (int nf = 0; nf < 4; ++nf) {
        int col = wave * 64 + nf * 16 + lr;
        float bias = b_out[col];
#pragma unroll
        for (int mf = 0; mf < 2; ++mf)
#pragma unroll
            for (int r = 0; r < 4; ++r) {
                int m = bm + mf * 16 + q * 4 + r;
                out[(size_t)m * CC + col] = acc[mf][nf][r] + bias;
            }
    }
}

extern "C" void kernel_launch(void* const* d_in, const int* in_sizes, int n_in,
                              void* d_out, int out_size, void* d_ws, size_t ws_size,
                              hipStream_t stream) {
    const float* query  = (const float*)d_in[0];
    const float* value  = (const float*)d_in[1];
    const float* refp   = (const float*)d_in[2];
    const float* W_off  = (const float*)d_in[3];
    const float* b_off  = (const float*)d_in[4];
    const float* W_attn = (const float*)d_in[5];
    const float* b_attn = (const float*)d_in[6];
    const float* W_val  = (const float*)d_in[7];
    const float* b_val  = (const float*)d_in[8];
    const float* W_out  = (const float*)d_in[9];
    const float* b_out  = (const float*)d_in[10];
    float* out = (float*)d_out;

    char* ws = (char*)d_ws;
    unsigned short* WTf    = (unsigned short*)(ws);                  // 128 KB
    unsigned short* v_ws   = (unsigned short*)(ws + 131072);         // 44.56 MB
    unsigned short* W1T    = (unsigned short*)(ws + 44695552);       // 96 KB
    unsigned short* WoT    = (unsigned short*)(ws + 44793856);       // 128 KB
    float*          logits = (float*)(ws + 44924928);                // 3 MB
    unsigned short* mid    = (unsigned short*)(ws + 47996928);       // 2 MB

    prep_kernel<<<CC, 256, 0, stream>>>(W_val, W_off, W_attn, W_out,
                                        WTf, W1T, WoT);
    valproj_mfma<<<(BB * NVV) / 32, 256, 0, stream>>>(value, WTf, b_val, v_ws);
    logits_mfma<<<NQT / 32, 256, 0, stream>>>(query, W1T, b_off, b_attn, logits);
    sample_kernel<<<NQT, 256, 0, stream>>>(logits, refp, v_ws, mid);
    out_mfma<<<NQT / 32, 256, 0, stream>>>(mid, WoT, b_out, out);
}

// Round 17
// 54.999 us; speedup vs baseline: 1.7005x; 1.7005x over previous
//
#include <hip/hip_runtime.h>

#define HH 8
#define LL 4
#define PP 2
#define DD 32
#define CC 256
#define NVV 21760
#define NQQ 1000
#define BB 4
#define NQT (BB * NQQ)   // 4000 total queries
#define NLOGB (NQT / 32) // 125 logits blocks
#define NVALB ((BB * NVV) / 64)  // 1360 valproj blocks

typedef __attribute__((ext_vector_type(8))) short short8;
typedef __attribute__((ext_vector_type(4))) short shortv4;
typedef __attribute__((ext_vector_type(4))) float f32x4;

__device__ __forceinline__ unsigned short f2bf(float f) {
    unsigned u = __float_as_uint(f);
    u += 0x7FFF + ((u >> 16) & 1);  // round-to-nearest-even
    return (unsigned short)(u >> 16);
}
__device__ __forceinline__ float bf2f(unsigned short h) {
    return __uint_as_float(((unsigned)h) << 16);
}
__device__ __forceinline__ unsigned cvtpk(float lo, float hi) {
    unsigned r;
    asm volatile("v_cvt_pk_bf16_f32 %0, %1, %2" : "=v"(r) : "v"(lo), "v"(hi));
    return r;
}

__device__ __forceinline__ void gload_lds16(const void* g, void* l) {
    __builtin_amdgcn_global_load_lds(
        (const __attribute__((address_space(1))) unsigned int*)g,
        (__attribute__((address_space(3))) unsigned int*)l, 16, 0, 0);
}

// ---------------------------------------------------------------------------
// Kernel 0: weight prep. Block c (=k row, 0..255), thread n. Coalesced reads.
//  WTs: window-major [s=k>>5][n][32 k] bf16, XOR-baked (R8-R10-proven:
//       0 LDS bank conflicts). Window = 16 KB contiguous -> linear DMA.
//  W1T[n][c] = bf16([W_off|W_attn][c][n]),  WoT[n][c] = bf16(W_out[c][n])
// ---------------------------------------------------------------------------
__global__ __launch_bounds__(256) void prep_kernel(
    const float* __restrict__ Wv, const float* __restrict__ Woff,
    const float* __restrict__ Wattn, const float* __restrict__ Wout,
    unsigned short* __restrict__ WTs, unsigned short* __restrict__ W1T,
    unsigned short* __restrict__ WoT)
{
    const int c = blockIdx.x;   // k index 0..255
    const int n = threadIdx.x;  // output col 0..255
    {
        int s = c >> 5, t = c & 31;
        WTs[s * 8192 + n * 32 + (t ^ (((n >> 1) & 3) << 3))] =
            f2bf(Wv[c * CC + n]);
    }
    if (n < 192) {
        float x = (n < 128) ? Woff[c * 128 + n] : Wattn[c * 64 + (n - 128)];
        W1T[n * CC + c] = f2bf(x);
    }
    WoT[n * CC + c] = f2bf(Wout[c * CC + n]);
}

// ---------------------------------------------------------------------------
// Kernel 1 (FUSED): blocks 0..124 = logits GEMM; blocks 125..1484 = valproj.
// The two are independent; fusing lets logits' MFMA-heavy blocks execute in
// the memory-stall shadow of valproj's blocks (valproj: MfmaUtil ~7%,
// VALUBusy ~7% -> CUs are mostly idle waiting on memory). valproj body is
// the R10 kernel VERBATIM (best measured: counted-vmcnt, BM=64, dual DMA,
// 0 bank conflicts). logits body is the R10 logits kernel verbatim.
// ---------------------------------------------------------------------------
__global__ __launch_bounds__(256, 3) void val_logits_fused(
    const float* __restrict__ value, const unsigned short* __restrict__ WTs,
    const float* __restrict__ bv, unsigned short* __restrict__ v_out,
    const float* __restrict__ query, const unsigned short* __restrict__ W1T,
    const float* __restrict__ b_off, const float* __restrict__ b_attn,
    float* __restrict__ logits)
{
    __shared__ __align__(16) char lds[49152];  // 48 KB union

    const int tid = threadIdx.x;
    const int lane = tid & 63;

    if (blockIdx.x >= NLOGB) {
        // ================= valproj branch (R10 verbatim) =================
        char (*Abuf)[8192] = (char (*)[8192])(lds);           // 2 x 8 KB
        char (*Bbuf)[16384] = (char (*)[16384])(lds + 16384); // 2 x 16 KB

        const int w = tid >> 6;        // wave 0..3
        const int wm = w >> 1;         // 32-row strip
        const int wn = w & 1;          // 128-col half
        const int lr = lane & 15;
        const int q = lane >> 4;       // k-chunk pair / row-quad
        const int bm = (blockIdx.x - NLOGB) * 64;

#define STAGE(s, bi)                                                        \
    {                                                                       \
        _Pragma("unroll") for (int r = 0; r < 2; ++r) {                     \
            int u = r * 256 + tid;                                          \
            int m = u >> 3, c = u & 7;                                      \
            gload_lds16((const char*)value + (size_t)(bm + m) * 1024 +      \
                            (s) * 128 + ((c ^ (m & 7)) * 16),               \
                        &Abuf[bi][u * 16]);                                 \
        }                                                                   \
        _Pragma("unroll") for (int r = 0; r < 4; ++r) {                     \
            int off = (r * 256 + tid) * 16;                                 \
            gload_lds16((const char*)WTs + (s) * 16384 + off,               \
                        &Bbuf[bi][off]);                                    \
        }                                                                   \
    }

        f32x4 acc[2][8] = {};

        STAGE(0, 0);
        STAGE(1, 1);   // 12 DMA outstanding per thread

#pragma unroll
        for (int s = 0; s < 8; ++s) {
            const int cur = s & 1;
            if (s < 7) {
                asm volatile("s_waitcnt vmcnt(6)" ::: "memory");
            } else {
                asm volatile("s_waitcnt vmcnt(0)" ::: "memory");
            }
            __builtin_amdgcn_s_barrier();
            __builtin_amdgcn_sched_barrier(0);

            short8 af[2];
#pragma unroll
            for (int mf = 0; mf < 2; ++mf) {
                int m = wm * 32 + mf * 16 + lr;
                const char* base = &Abuf[cur][m * 128];
                f32x4 lo = *(const f32x4*)(base + (((2 * q) ^ (m & 7)) * 16));
                f32x4 hi =
                    *(const f32x4*)(base + (((2 * q + 1) ^ (m & 7)) * 16));
                uint4 uv = {cvtpk(lo[0], lo[1]), cvtpk(lo[2], lo[3]),
                            cvtpk(hi[0], hi[1]), cvtpk(hi[2], hi[3])};
                af[mf] = __builtin_bit_cast(short8, uv);
            }
#pragma unroll
            for (int nf = 0; nf < 8; ++nf) {
                int n = wn * 128 + nf * 16 + lr;
                short8 bf = *(const short8*)&Bbuf[cur]
                                [n * 64 + ((q ^ ((n >> 1) & 3)) * 16)];
                acc[0][nf] = __builtin_amdgcn_mfma_f32_16x16x32_bf16(
                    af[0], bf, acc[0][nf], 0, 0, 0);
                acc[1][nf] = __builtin_amdgcn_mfma_f32_16x16x32_bf16(
                    af[1], bf, acc[1][nf], 0, 0, 0);
            }

            __builtin_amdgcn_s_barrier();
            __builtin_amdgcn_sched_barrier(0);
            if (s < 6) STAGE(s + 2, cur);
        }
#undef STAGE

#pragma unroll
        for (int nf = 0; nf < 8; ++nf) {
            int col = wn * 128 + nf * 16 + lr;
            float bias = bv[col];
#pragma unroll
            for (int mf = 0; mf < 2; ++mf) {
                size_t rbase =
                    (size_t)(bm + wm * 32 + mf * 16 + q * 4) * 256 + col;
#pragma unroll
                for (int r = 0; r < 4; ++r)
                    v_out[rbase + (size_t)r * 256] =
                        f2bf(acc[mf][nf][r] + bias);
            }
        }
    } else {
        // ================= logits branch (R10 verbatim) =================
        unsigned short (*As)[72] = (unsigned short (*)[72])(lds);
        unsigned short (*Bsl)[72] = (unsigned short (*)[72])(lds + 4608);

        const int wave = tid >> 6;
        const int bm = blockIdx.x * 32;
        const int lr = lane & 15;
        const int q = lane >> 4;
        f32x4 acc[2][3] = {};

        for (int k0 = 0; k0 < CC; k0 += 64) {
            float4 a[2];
            short8 wv[6];
#pragma unroll
            for (int i = 0; i < 2; ++i) {
                int u = tid + 256 * i;
                a[i] = *(const float4*)&query[(size_t)(bm + (u >> 4)) * CC +
                                              k0 + (u & 15) * 4];
            }
#pragma unroll
            for (int i = 0; i < 6; ++i) {
                int u = tid + 256 * i;
                wv[i] = *(const short8*)&W1T[(size_t)(u >> 3) * CC + k0 +
                                             (u & 7) * 8];
            }
            __syncthreads();
#pragma unroll
            for (int i = 0; i < 2; ++i) {
                int u = tid + 256 * i;
                shortv4 p;
                p[0] = (short)f2bf(a[i].x); p[1] = (short)f2bf(a[i].y);
                p[2] = (short)f2bf(a[i].z); p[3] = (short)f2bf(a[i].w);
                *(shortv4*)&As[u >> 4][(u & 15) * 4] = p;
            }
#pragma unroll
            for (int i = 0; i < 6; ++i) {
                int u = tid + 256 * i;
                *(short8*)&Bsl[u >> 3][(u & 7) * 8] = wv[i];
            }
            __syncthreads();

#pragma unroll
            for (int kk = 0; kk < 2; ++kk) {
                short8 afr[2], bfr[3];
#pragma unroll
                for (int mf = 0; mf < 2; ++mf)
                    afr[mf] = *(const short8*)&As[mf * 16 + lr][kk * 32 + q * 8];
#pragma unroll
                for (int nf = 0; nf < 3; ++nf)
                    bfr[nf] = *(const short8*)&Bsl[wave * 48 + nf * 16 + lr]
                                                 [kk * 32 + q * 8];
#pragma unroll
                for (int mf = 0; mf < 2; ++mf)
#pragma unroll
                    for (int nf = 0; nf < 3; ++nf)
                        acc[mf][nf] = __builtin_amdgcn_mfma_f32_16x16x32_bf16(
                            afr[mf], bfr[nf], acc[mf][nf], 0, 0, 0);
            }
            __syncthreads();
        }

#pragma unroll
        for (int nf = 0; nf < 3; ++nf) {
            int col = wave * 48 + nf * 16 + lr;
            float bias = (col < 128) ? b_off[col] : b_attn[col - 128];
#pragma unroll
            for (int mf = 0; mf < 2; ++mf)
#pragma unroll
                for (int r = 0; r < 4; ++r) {
                    int m = bm + mf * 16 + q * 4 + r;
                    logits[(size_t)m * 192 + col] = acc[mf][nf][r] + bias;
                }
        }
    }
}

// ---------------------------------------------------------------------------
// Kernel 2: sampling. One block per query (4000 blocks). Fuses softmax.
// v is ROW-MAJOR [b*NVV+n][256]; thread (h,d) gathers 8 samples x 4 corners.
// ---------------------------------------------------------------------------
__global__ __launch_bounds__(256) void sample_kernel(
    const float* __restrict__ logits,  // [4000][192]
    const float* __restrict__ refp,    // [B,NQ,L,2]
    const unsigned short* __restrict__ v,  // [B*NV][256] bf16
    unsigned short* __restrict__ mid)      // [4000][256] bf16
{
    __shared__ float offl[128];
    __shared__ float attnl[64];
    __shared__ float refl[8];

    const int qy = blockIdx.x;  // b*NQQ + nq
    const int b = qy / NQQ;
    const int tid = threadIdx.x;

    if (tid < 192) {
        float t = logits[(size_t)qy * 192 + tid];
        if (tid < 128) offl[tid] = t;
        else attnl[tid - 128] = t;
    } else if (tid < 200) {
        refl[tid - 192] = refp[(size_t)qy * 8 + (tid - 192)];
    }
    __syncthreads();

    if (tid < 8) {
        float m = -1e30f;
#pragma unroll
        for (int j = 0; j < 8; ++j) m = fmaxf(m, attnl[tid * 8 + j]);
        float s = 0.f, e[8];
#pragma unroll
        for (int j = 0; j < 8; ++j) {
            e[j] = __expf(attnl[tid * 8 + j] - m);
            s += e[j];
        }
        float inv = 1.f / s;
#pragma unroll
        for (int j = 0; j < 8; ++j) attnl[tid * 8 + j] = e[j] * inv;
    }
    __syncthreads();

    const int h = tid >> 5, d = tid & 31;
    const int starts[4] = {0, 16384, 20480, 21504};
    const float szs[4] = {128.f, 64.f, 32.f, 16.f};

    float acc = 0.f;
#pragma unroll
    for (int l = 0; l < LL; ++l) {
        const float S = szs[l];
        const int Wl = (int)S;
        const float refx = refl[l * 2 + 0];
        const float refy = refl[l * 2 + 1];
        const unsigned short* vl =
            v + (size_t)(b * NVV + starts[l]) * 256 + h * 32 + d;
#pragma unroll
        for (int p = 0; p < PP; ++p) {
            const int oi = h * 16 + l * 4 + p * 2;
            float lx = refx + offl[oi + 0] / S;
            float ly = refy + offl[oi + 1] / S;
            float x = lx * S - 0.5f;
            float y = ly * S - 0.5f;
            float x0f = floorf(x), y0f = floorf(y);
            float fx = x - x0f, fy = y - y0f;
            int x0 = (int)x0f, y0 = (int)y0f;
            float a = attnl[h * 8 + l * 2 + p];
            float sacc = 0.f;
#pragma unroll
            for (int dy = 0; dy < 2; ++dy) {
#pragma unroll
                for (int dx = 0; dx < 2; ++dx) {
                    int xi = x0 + dx, yi = y0 + dy;
                    float wgt = (dx ? fx : 1.f - fx) * (dy ? fy : 1.f - fy);
                    bool valid = (xi >= 0) && (xi < Wl) && (yi >= 0) && (yi < Wl);
                    int xc = min(max(xi, 0), Wl - 1);
                    int yc = min(max(yi, 0), Wl - 1);
                    float g = bf2f(vl[(size_t)(yc * Wl + xc) * 256]);
                    sacc += g * (valid ? wgt : 0.f);
                }
            }
            acc += a * sacc;
        }
    }
    mid[(size_t)qy * CC + h * 32 + d] = f2bf(acc);
}

// ---------------------------------------------------------------------------
// Kernel 3: out[4000,256] = mid_bf16 @ W_out_bf16 + b_out.
// BM=32, BK=64 (4 iters), 4 waves x 64 cols. Padded LDS rows (72).
// ---------------------------------------------------------------------------
__global__ __launch_bounds__(256) void out_mfma(
    const unsigned short* __restrict__ mid,
    const unsigned short* __restrict__ WoT, const float* __restrict__ b_out,
    float* __restrict__ out)
{
    __shared__ unsigned short As[32][72];
    __shared__ unsigned short Bso[256][72];
    const int tid = threadIdx.x;
    const int lane = tid & 63;
    const int wave = tid >> 6;
    const int bm = blockIdx.x * 32;
    const int lr = lane & 15;
    const int q = lane >> 4;
    f32x4 acc[2][4] = {};

    for (int k0 = 0; k0 < CC; k0 += 64) {
        short8 a0 = *(const short8*)&mid[(size_t)(bm + (tid >> 3)) * CC + k0 +
                                         (tid & 7) * 8];
        short8 wv[8];
#pragma unroll
        for (int i = 0; i < 8; ++i) {
            int u = tid + 256 * i;  // 2048 16B units: n=u>>3, j=u&7
            wv[i] = *(const short8*)&WoT[(size_t)(u >> 3) * CC + k0 + (u & 7) * 8];
        }
        __syncthreads();
        *(short8*)&As[tid >> 3][(tid & 7) * 8] = a0;
#pragma unroll
        for (int i = 0; i < 8; ++i) {
            int u = tid + 256 * i;
            *(short8*)&Bso[u >> 3][(u & 7) * 8] = wv[i];
        }
        __syncthreads();

#pragma unroll
        for (int kk = 0; kk < 2; ++kk) {
            short8 afr[2], bfr[4];
#pragma unroll
            for (int mf = 0; mf < 2; ++mf)
                afr[mf] = *(const short8*)&As[mf * 16 + lr][kk * 32 + q * 8];
#pragma unroll
            for (int nf = 0; nf < 4; ++nf)
                bfr[nf] =
                    *(const short8*)&Bso[wave * 64 + nf * 16 + lr][kk * 32 + q * 8];
#pragma unroll
            for (int mf = 0; mf < 2; ++mf)
#pragma unroll
                for (int nf = 0; nf < 4; ++nf)
                    acc[mf][nf] = __builtin_amdgcn_mfma_f32_16x16x32_bf16(
                        afr[mf], bfr[nf], acc[mf][nf], 0, 0, 0);
        }
        __syncthreads();
    }

#pragma unroll
    for (int nf = 0; nf < 4; ++nf) {
        int col = wave * 64 + nf * 16 + lr;
        float bias = b_out[col];
#pragma unroll
        for (int mf = 0; mf < 2; ++mf)
#pragma unroll
            for (int r = 0; r < 4; ++r) {
                int m = bm + mf * 16 + q * 4 + r;
                out[(size_t)m * CC + col] = acc[mf][nf][r] + bias;
            }
    }
}

extern "C" void kernel_launch(void* const* d_in, const int* in_sizes, int n_in,
                              void* d_out, int out_size, void* d_ws, size_t ws_size,
                              hipStream_t stream) {
    const float* query  = (const float*)d_in[0];
    const float* value  = (const float*)d_in[1];
    const float* refp   = (const float*)d_in[2];
    const float* W_off  = (const float*)d_in[3];
    const float* b_off  = (const float*)d_in[4];
    const float* W_attn = (const float*)d_in[5];
    const float* b_attn = (const float*)d_in[6];
    const float* W_val  = (const float*)d_in[7];
    const float* b_val  = (const float*)d_in[8];
    const float* W_out  = (const float*)d_in[9];
    const float* b_out  = (const float*)d_in[10];
    float* out = (float*)d_out;

    char* ws = (char*)d_ws;
    unsigned short* WTs    = (unsigned short*)(ws);                  // 128 KB
    unsigned short* v_ws   = (unsigned short*)(ws + 131072);         // 44.56 MB
    unsigned short* W1T    = (unsigned short*)(ws + 44695552);       // 96 KB
    unsigned short* WoT    = (unsigned short*)(ws + 44793856);       // 128 KB
    float*          logits = (float*)(ws + 44924928);                // 3 MB
    unsigned short* mid    = (unsigned short*)(ws + 47996928);       // 2 MB

    prep_kernel<<<CC, 256, 0, stream>>>(W_val, W_off, W_attn, W_out,
                                        WTs, W1T, WoT);
    val_logits_fused<<<NLOGB + NVALB, 256, 0, stream>>>(
        value, WTs, b_val, v_ws, query, W1T, b_off, b_attn, logits);
    sample_kernel<<<NQT, 256, 0, stream>>>(logits, refp, v_ws, mid);
    out_mfma<<<NQT / 32, 256, 0, stream>>>(mid, WoT, b_out, out);
}